// Round 17
// baseline (173.621 us; speedup 1.0000x reference)
//
#include <hip/hip_runtime.h>
#include <float.h>
#include <math.h>

#define SEQ 2048
#define NB 4
#define DIM 128
#define DL 16
#define NEGV (-1e9f)
#define TOPK 8

#define QT 128      // q-rows per out block
#define KC 64       // k chunk staged in LDS (out kernel)
#define QCH 64      // q-chunk for colred fallback

typedef unsigned long long u64;
typedef __attribute__((ext_vector_type(8))) short short8;
typedef __attribute__((ext_vector_type(4))) float f32x4;

__device__ __forceinline__ void top8_insert(float* s, float key) {
    #pragma unroll
    for (int i = 0; i < 8; ++i) {
        float a = s[i];
        s[i] = fmaxf(a, key);
        key  = fminf(a, key);
    }
}

// merge sorted-desc top8s across the 16 lanes of a quad group (xor 1,2,4,8)
__device__ __forceinline__ float top8_merge16(float* s) {
    #pragma unroll
    for (int off = 1; off < 16; off <<= 1) {
        float o[8], t[8];
        #pragma unroll
        for (int i = 0; i < 8; ++i)
            o[i] = __shfl_xor(s[i], off, 64);
        #pragma unroll
        for (int i = 0; i < 8; ++i)
            t[i] = fmaxf(s[i], o[7 - i]);
        #pragma unroll
        for (int i = 0; i < 4; ++i) {
            float a = t[i], c = t[i + 4];
            t[i] = fmaxf(a, c); t[i + 4] = fminf(a, c);
        }
        #pragma unroll
        for (int g2 = 0; g2 < 8; g2 += 4) {
            float a = t[g2], c = t[g2 + 2];
            t[g2] = fmaxf(a, c); t[g2 + 2] = fminf(a, c);
            a = t[g2 + 1]; c = t[g2 + 3];
            t[g2 + 1] = fmaxf(a, c); t[g2 + 3] = fminf(a, c);
        }
        #pragma unroll
        for (int g1 = 0; g1 < 8; g1 += 2) {
            float a = t[g1], c = t[g1 + 1];
            t[g1] = fmaxf(a, c); t[g1 + 1] = fminf(a, c);
        }
        #pragma unroll
        for (int i = 0; i < 8; ++i) s[i] = t[i];
    }
    return s[7];
}

// bf16 round-to-nearest-even of f32 (returns 16-bit pattern)
__device__ __forceinline__ unsigned bf16_rne(float x) {
    unsigned u = __float_as_uint(x);
    return (u + 0x7FFFu + ((u >> 16) & 1u)) >> 16;
}

// ---------------------------------------------------------------------------
// Kernel A: projections. Emits PACKED bf16 MFMA operands for the score GEMM
// (3-way split, see r12) + sh[k].
// ---------------------------------------------------------------------------
__global__ __launch_bounds__(256) void proj_kernel(
    const float* __restrict__ q, const float* __restrict__ k,
    const float* __restrict__ Wql, const float* __restrict__ bql,
    const float* __restrict__ Wkl, const float* __restrict__ bkl,
    const float* __restrict__ Wqh, const float* __restrict__ bqh,
    const float* __restrict__ Wkh, const float* __restrict__ bkh,
    unsigned short* __restrict__ qA1, unsigned short* __restrict__ qA2,
    unsigned short* __restrict__ qA3,
    unsigned short* __restrict__ kB1, unsigned short* __restrict__ kB2,
    float* __restrict__ sh)
{
    __shared__ float Ws[4][DIM * DL];
    __shared__ float rowq[16][DIM];
    __shared__ float rowk[16][DIM];
    int tid = threadIdx.x;
    for (int i = tid; i < DIM * DL; i += 256) {
        Ws[0][i] = Wql[i];
        Ws[1][i] = Wkl[i];
        Ws[2][i] = Wqh[i];
        Ws[3][i] = Wkh[i];
    }
    int r0 = blockIdx.x * 16;
    for (int i = tid; i < 16 * DIM; i += 256) {
        int rr = i >> 7, cc = i & 127;
        rowq[rr][cc] = q[(size_t)(r0 + rr) * DIM + cc];
        rowk[rr][cc] = k[(size_t)(r0 + rr) * DIM + cc];
    }
    __syncthreads();
    int g = tid >> 4;
    int e = tid & 15;
    float aql = 0.f, akl = 0.f, aqh = 0.f, akh = 0.f;
    #pragma unroll 8
    for (int i = 0; i < DIM; ++i) {
        float qv = rowq[g][i], kv = rowk[g][i];
        aql = fmaf(qv, Ws[0][i * DL + e], aql);
        akl = fmaf(kv, Ws[1][i * DL + e], akl);
        aqh = fmaf(qv, Ws[2][i * DL + e], aqh);
        akh = fmaf(kv, Ws[3][i * DL + e], akh);
    }
    int t = r0 + g;
    float qv = aql + bql[e];
    float kv = akl + bkl[e];

    unsigned q1 = bf16_rne(qv);
    float q1f = __uint_as_float(q1 << 16);
    float qr1 = qv - q1f;
    unsigned q2 = bf16_rne(qr1);
    float q2f = __uint_as_float(q2 << 16);
    unsigned q3 = bf16_rne(qr1 - q2f);

    unsigned k1 = bf16_rne(kv);
    float k1f = __uint_as_float(k1 << 16);
    float kr1 = kv - k1f;
    unsigned k2 = bf16_rne(kr1);
    float k2f = __uint_as_float(k2 << 16);
    unsigned k3 = bf16_rne(kr1 - k2f);

    size_t pb = (size_t)t * 32;
    qA1[pb + e] = (unsigned short)q1; qA1[pb + 16 + e] = (unsigned short)q2;
    qA2[pb + e] = (unsigned short)q2; qA2[pb + 16 + e] = (unsigned short)q1;
    qA3[pb + e] = (unsigned short)q1; qA3[pb + 16 + e] = (unsigned short)q3;
    kB1[pb + e] = (unsigned short)k1; kB1[pb + 16 + e] = (unsigned short)k2;
    kB2[pb + e] = (unsigned short)k3; kB2[pb + 16 + e] = (unsigned short)k1;

    float qp = aqh + bqh[e];
    float kp = akh + bkh[e];
    float prod = qp * kp;
    #pragma unroll
    for (int off = 8; off >= 1; off >>= 1)
        prod += __shfl_xor(prod, off, 16);
    if (e == 0) sh[t] = 0.25f * prod;
}

// ---------------------------------------------------------------------------
// Kernel A2: V transpose + bf16 hi/lo split: VthH/VthL[b][d][k].
// ---------------------------------------------------------------------------
__global__ __launch_bounds__(256) void vsplit_kernel(
    const float* __restrict__ V, unsigned short* __restrict__ VH,
    unsigned short* __restrict__ VL)
{
    __shared__ float T[32][33];
    int kb = blockIdx.x * 32, db = blockIdx.y * 32, b = blockIdx.z;
    int tid = threadIdx.x;
    {
        int r = tid >> 3, cg = tid & 7;
        float4 v = *(const float4*)(V + ((size_t)b * SEQ + kb + r) * DIM + db + cg * 4);
        T[r][cg * 4 + 0] = v.x; T[r][cg * 4 + 1] = v.y;
        T[r][cg * 4 + 2] = v.z; T[r][cg * 4 + 3] = v.w;
    }
    __syncthreads();
    int dr = tid >> 3, kg = tid & 7;
    unsigned h[4], l[4];
    #pragma unroll
    for (int j = 0; j < 4; ++j) {
        float f = T[kg * 4 + j][dr];
        unsigned hi = bf16_rne(f);
        float hf = __uint_as_float(hi << 16);
        unsigned lo = bf16_rne(f - hf);
        h[j] = hi; l[j] = lo;
    }
    size_t o = ((size_t)b * DIM + db + dr) * SEQ + kb + kg * 4;
    *(uint2*)(VH + o) = make_uint2(h[0] | (h[1] << 16), h[2] | (h[3] << 16));
    *(uint2*)(VL + o) = make_uint2(l[0] | (l[1] << 16), l[2] | (l[3] << 16));
}

// ---------------------------------------------------------------------------
// Kernel B v15: two-pass MFMA score (r16 structure) with max-then-sum stats:
// pass-2 column partials use 3 parallel fmax + 4 independent exp per tile
// instead of the serial online chain (8 exp) — same math, less trans-pipe
// work and no dependent chain (r16: VALUBusy 46% at 18% occupancy).
// S is stored PRE-PATCHED (single patch site).
// ---------------------------------------------------------------------------
__global__ __launch_bounds__(256) void score_mfma(
    const unsigned short* __restrict__ qA1, const unsigned short* __restrict__ qA2,
    const unsigned short* __restrict__ qA3,
    const unsigned short* __restrict__ kB1, const unsigned short* __restrict__ kB2,
    const int* __restrict__ valid_lens, const float* __restrict__ sh,
    float* __restrict__ Smat, float2* __restrict__ pml, int do_stats)
{
    __shared__ float red[4][16][8];   // [wave][row][top8]
    __shared__ float thr_s[16];

    int tid  = threadIdx.x;
    int lane = tid & 63;
    int wv   = tid >> 6;
    int c15  = lane & 15;
    int g    = lane >> 4;                       // quad
    int row0 = __builtin_amdgcn_readfirstlane(blockIdx.x * 16);
    int b    = row0 >> 11;
    int qi0  = row0 & (SEQ - 1);

    // A fragments (whole kernel): A[row=lane&15][k=quad*8+j]
    size_t aoff = (size_t)(row0 + c15) * 32 + g * 8;
    short8 A1 = *(const short8*)(qA1 + aoff);
    short8 A2 = *(const short8*)(qA2 + aoff);
    short8 A3 = *(const short8*)(qA3 + aoff);

    const unsigned short* kb1 = kB1 + (size_t)b * SEQ * 32;
    const unsigned short* kb2 = kB2 + (size_t)b * SEQ * 32;
    const int* vlb = valid_lens + (size_t)b * SEQ;

    float s8[4][8];
    #pragma unroll
    for (int r = 0; r < 4; ++r)
        #pragma unroll
        for (int i = 0; i < 8; ++i) s8[r][i] = -FLT_MAX;

    int rowg[4];
    #pragma unroll
    for (int r = 0; r < 4; ++r) rowg[r] = qi0 + g * 4 + r;

    // ---- pass 1: top-8 only (no stores)
    #pragma unroll
    for (int t = 0; t < 32; ++t) {
        int col = (wv * 32 + t) * 16 + c15;
        size_t boff = (size_t)col * 32 + g * 8;  // B[k=quad*8+j][col]
        short8 B1 = *(const short8*)(kb1 + boff);
        short8 B2 = *(const short8*)(kb2 + boff);

        f32x4 acc = (f32x4){0.f, 0.f, 0.f, 0.f};
        acc = __builtin_amdgcn_mfma_f32_16x16x32_bf16(A1, B1, acc, 0, 0, 0);
        acc = __builtin_amdgcn_mfma_f32_16x16x32_bf16(A2, B1, acc, 0, 0, 0);
        acc = __builtin_amdgcn_mfma_f32_16x16x32_bf16(A3, B2, acc, 0, 0, 0);

        int vl = vlb[col];
        vl = vl < 0 ? 0 : (vl > SEQ - 1 ? SEQ - 1 : vl);

        // C layout: col = lane&15, row = quad*4 + reg
        #pragma unroll
        for (int r = 0; r < 4; ++r) {
            float v = 0.25f * acc[r];
            if (vl == rowg[r]) v += NEGV;
            top8_insert(s8[r], v);
        }
    }

    // merge the 16 col-slices within each quad (rows g*4+r)
    #pragma unroll
    for (int r = 0; r < 4; ++r) top8_merge16(s8[r]);

    // cross-wave merge via LDS
    if (c15 == 0) {
        #pragma unroll
        for (int r = 0; r < 4; ++r)
            #pragma unroll
            for (int i = 0; i < 8; ++i)
                red[wv][g * 4 + r][i] = s8[r][i];
    }
    __syncthreads();
    if (tid < 16) {
        float fin[8];
        #pragma unroll
        for (int i = 0; i < 8; ++i) fin[i] = red[0][tid][i];
        #pragma unroll
        for (int w2 = 1; w2 < 4; ++w2)
            #pragma unroll
            for (int i = 0; i < 8; ++i)
                top8_insert(fin, red[w2][tid][i]);
        thr_s[tid] = fin[7];
    }
    __syncthreads();   // publish thr_s

    // ---- pass 2: recompute (bit-identical), patch, store patched S, stats
    const float* shb = sh + (size_t)b * SEQ;
    int chunk = qi0 >> 4;   // 0..127 within batch
    float thr_l[4];
    #pragma unroll
    for (int r = 0; r < 4; ++r) thr_l[r] = thr_s[g * 4 + r];

    #pragma unroll
    for (int t = 0; t < 32; ++t) {
        int col = (wv * 32 + t) * 16 + c15;
        size_t boff = (size_t)col * 32 + g * 8;
        short8 B1 = *(const short8*)(kb1 + boff);
        short8 B2 = *(const short8*)(kb2 + boff);

        f32x4 acc = (f32x4){0.f, 0.f, 0.f, 0.f};
        acc = __builtin_amdgcn_mfma_f32_16x16x32_bf16(A1, B1, acc, 0, 0, 0);
        acc = __builtin_amdgcn_mfma_f32_16x16x32_bf16(A2, B1, acc, 0, 0, 0);
        acc = __builtin_amdgcn_mfma_f32_16x16x32_bf16(A3, B2, acc, 0, 0, 0);

        int vl = vlb[col];
        vl = vl < 0 ? 0 : (vl > SEQ - 1 ? SEQ - 1 : vl);
        float shk = shb[col];

        float* So = Smat + (size_t)(row0 + g * 4) * SEQ + col;
        float e[4];
        #pragma unroll
        for (int r = 0; r < 4; ++r) {
            float v = 0.25f * acc[r];
            if (vl == rowg[r]) v += NEGV;
            v = (v >= thr_l[r]) ? shk : v;     // top-8 patch (single site)
            So[(size_t)r * SEQ] = v;
            e[r] = v;
        }
        if (do_stats) {
            // max-then-sum: parallel fmax tree + 4 independent exps
            float m = fmaxf(fmaxf(e[0], e[1]), fmaxf(e[2], e[3]));
            float l = __expf(e[0] - m) + __expf(e[1] - m)
                    + __expf(e[2] - m) + __expf(e[3] - m);
            // merge across the 4 quads (lane bits 4 and 5)
            #pragma unroll
            for (int off = 16; off <= 32; off <<= 1) {
                float mo = __shfl_xor(m, off, 64);
                float lo = __shfl_xor(l, off, 64);
                float nm = fmaxf(m, mo);
                l = l * __expf(m - nm) + lo * __expf(mo - nm);
                m = nm;
            }
            if (g == 0)
                pml[((size_t)b * 128 + chunk) * SEQ + col] = make_float2(m, l);
        }
    }
}

// ---------------------------------------------------------------------------
// Kernel C (fused, tier-2 path): final column stats over 128 chunks.
// ---------------------------------------------------------------------------
__global__ __launch_bounds__(256) void colred_final2(
    const float2* __restrict__ pml,
    float* __restrict__ cmax, float* __restrict__ cinv)
{
    __shared__ float2 red[4][64];
    int tid = threadIdx.x;
    int c0 = tid & 63, sl = tid >> 6;
    int gcol = blockIdx.x * 64 + c0;       // 0..8191
    int b = gcol >> 11, kcol = gcol & (SEQ - 1);
    float m = -FLT_MAX, l = 0.f;
    #pragma unroll 8
    for (int i = 0; i < 32; ++i) {
        int c = sl * 32 + i;
        float2 p = pml[((size_t)b * 128 + c) * SEQ + kcol];
        float nm = fmaxf(m, p.x);
        l = l * __expf(m - nm) + p.y * __expf(p.x - nm);
        m = nm;
    }
    red[sl][c0] = make_float2(m, l);
    __syncthreads();
    if (sl == 0) {
        #pragma unroll
        for (int s = 1; s < 4; ++s) {
            float2 p = red[s][c0];
            float nm = fmaxf(m, p.x);
            l = l * __expf(m - nm) + p.y * __expf(p.x - nm);
            m = nm;
        }
        cmax[gcol] = m;
        cinv[gcol] = 1.f / l;
    }
}

// ---------------------------------------------------------------------------
// Fallback kernels (no pml space): colred on the PRE-PATCHED Smat.
// ---------------------------------------------------------------------------
__global__ __launch_bounds__(256) void colred_partial(
    const float* __restrict__ Smat, float* __restrict__ pm, float* __restrict__ pl)
{
    int kcol = blockIdx.x * 256 + threadIdx.x;
    int qc = blockIdx.y;
    int b  = blockIdx.z;
    const float* Sp = Smat + (size_t)b * SEQ * SEQ + (size_t)(qc * QCH) * SEQ + kcol;
    float m = -FLT_MAX, l = 0.f;
    #pragma unroll 4
    for (int qq = 0; qq < QCH; ++qq) {
        float v = Sp[(size_t)qq * SEQ];
        float nm = fmaxf(m, v);
        l = l * __expf(m - nm) + __expf(v - nm);
        m = nm;
    }
    pm[((size_t)b * 32 + qc) * SEQ + kcol] = m;
    pl[((size_t)b * 32 + qc) * SEQ + kcol] = l;
}

__global__ __launch_bounds__(256) void colred_final(
    const float* __restrict__ pm, const float* __restrict__ pl,
    float* __restrict__ cmax, float* __restrict__ cinv)
{
    int idx = blockIdx.x * 256 + threadIdx.x;
    int b = idx >> 11, kcol = idx & (SEQ - 1);
    float m = -FLT_MAX, l = 0.f;
    #pragma unroll
    for (int c = 0; c < 32; ++c) {
        float mm = pm[((size_t)b * 32 + c) * SEQ + kcol];
        float ll = pl[((size_t)b * 32 + c) * SEQ + kcol];
        float nm = fmaxf(m, mm);
        l = l * __expf(m - nm) + ll * __expf(mm - nm);
        m = nm;
    }
    cmax[idx] = m;
    cinv[idx] = 1.f / l;
}

// ---------------------------------------------------------------------------
// Kernel D v2: MFMA PV on PRE-PATCHED S. Column stats staged in LDS:
// infinal==1 -> computed in-kernel from pml (256 cols x 128 chunks, krange
// must be 256), deleting the colred_final2 dispatch; infinal==0 -> loaded
// from global cmax/cinv. P-phase reads LDS either way (branch-free).
// ---------------------------------------------------------------------------
__global__ __launch_bounds__(256) void out_mfma(
    const float* __restrict__ Smat, const unsigned short* __restrict__ VH,
    const unsigned short* __restrict__ VL,
    const float* __restrict__ cmax, const float* __restrict__ cinv,
    const float2* __restrict__ pml,
    float* __restrict__ dst, int krange, int infinal)
{
    __shared__ unsigned int VtH[DIM * 32];   // 16 KB, [d][k-words] XOR-swizzled
    __shared__ unsigned int VtL[DIM * 32];   // 16 KB
    __shared__ float cmx[2048];              // 8 KB (supports krange<=2048)
    __shared__ float cin[2048];              // 8 KB

    int tid  = threadIdx.x;
    int w    = tid >> 6;
    int lane = tid & 63;
    int ln   = lane & 15;
    int quad = lane >> 4;
    int q0   = blockIdx.x * QT;
    int ksid = blockIdx.y;
    int b    = blockIdx.z;
    int kbeg = ksid * krange;

    const float* Sb = Smat + (size_t)b * SEQ * SEQ;
    const unsigned short* VHb = VH + (size_t)b * DIM * SEQ;
    const unsigned short* VLb = VL + (size_t)b * DIM * SEQ;

    // ---- stats prologue into LDS
    if (infinal) {
        // krange == 256 guaranteed by launcher
        int col = kbeg + tid;
        const float2* pp = pml + (size_t)b * 128 * SEQ + col;
        float m = -FLT_MAX, l = 0.f;
        #pragma unroll 8
        for (int c = 0; c < 128; ++c) {
            float2 p = pp[(size_t)c * SEQ];
            float nm = fmaxf(m, p.x);
            l = l * __expf(m - nm) + p.y * __expf(p.x - nm);
            m = nm;
        }
        cmx[tid] = m;
        cin[tid] = 1.f / l;
    } else {
        for (int i = tid; i < krange; i += 256) {
            cmx[i] = cmax[(size_t)b * SEQ + kbeg + i];
            cin[i] = cinv[(size_t)b * SEQ + kbeg + i];
        }
    }
    __syncthreads();

    f32x4 acc[2][8];
    #pragma unroll
    for (int mt = 0; mt < 2; ++mt)
        #pragma unroll
        for (int nt = 0; nt < 8; ++nt)
            acc[mt][nt] = (f32x4){0.f, 0.f, 0.f, 0.f};

    int sd0   = tid >> 3;   // staging d row (0..31, +32/iter)
    int skseg = tid & 7;    // staging k-segment (16B granule)

    for (int k0 = kbeg; k0 < kbeg + krange; k0 += KC) {
        // stage V^T hi/lo chunk [128d][64k] bf16, XOR-swizzled 16B granules
        #pragma unroll
        for (int it = 0; it < 4; ++it) {
            int d = sd0 + it * 32;
            size_t go = (size_t)d * SEQ + k0 + skseg * 8;
            uint4 hv = *(const uint4*)(VHb + go);
            uint4 lv = *(const uint4*)(VLb + go);
            int wa = d * 32 + ((skseg ^ (d & 7)) << 2);
            *(uint4*)&VtH[wa] = hv;
            *(uint4*)&VtL[wa] = lv;
        }

        // P A-fragments (registers): lane holds P[q=mtile+ln][k=quad*8+j]
        short8 Ah[2][2], Al[2][2];
        #pragma unroll
        for (int ks = 0; ks < 2; ++ks) {
            int kk   = k0 + ks * 32 + quad * 8;
            int kloc = kk - kbeg;
            float4 cma = *(const float4*)(cmx + kloc);
            float4 cmb = *(const float4*)(cmx + kloc + 4);
            float4 cia = *(const float4*)(cin + kloc);
            float4 cib = *(const float4*)(cin + kloc + 4);
            #pragma unroll
            for (int mt = 0; mt < 2; ++mt) {
                const float* Sp = Sb + (size_t)(q0 + w * 32 + mt * 16 + ln) * SEQ + kk;
                float4 sa = *(const float4*)Sp;
                float4 sb = *(const float4*)(Sp + 4);
                float p[8];
                p[0] = __expf(sa.x - cma.x) * cia.x;
                p[1] = __expf(sa.y - cma.y) * cia.y;
                p[2] = __expf(sa.z - cma.z) * cia.z;
                p[3] = __expf(sa.w - cma.w) * cia.w;
                p[4] = __expf(sb.x - cmb.x) * cib.x;
                p[5] = __expf(sb.y - cmb.y) * cib.y;
                p[6] = __expf(sb.z - cmb.z) * cib.z;
                p[7] = __expf(sb.w - cmb.w) * cib.w;
                #pragma unroll
                for (int j = 0; j < 8; ++j) {
                    unsigned hi = bf16_rne(p[j]);
                    float hf = __uint_as_float(hi << 16);
                    unsigned lo = bf16_rne(p[j] - hf);
                    Ah[mt][ks][j] = (short)hi;
                    Al[mt][ks][j] = (short)lo;
                }
            }
        }
        __syncthreads();

        #pragma unroll
        for (int nt = 0; nt < 8; ++nt) {
            int d = nt * 16 + ln;
            #pragma unroll
            for (int ks = 0; ks < 2; ++ks) {
                int kseg = ks * 4 + quad;
                int wa = d * 32 + ((kseg ^ (d & 7)) << 2);
                short8 bh = *(short8*)&VtH[wa];
                short8 bl = *(short8*)&VtL[wa];
                #pragma unroll
                for (int mt = 0; mt < 2; ++mt) {
                    acc[mt][nt] = __builtin_amdgcn_mfma_f32_16x16x32_bf16(
                        Ah[mt][ks], bh, acc[mt][nt], 0, 0, 0);
                    acc[mt][nt] = __builtin_amdgcn_mfma_f32_16x16x32_bf16(
                        Al[mt][ks], bh, acc[mt][nt], 0, 0, 0);
                    acc[mt][nt] = __builtin_amdgcn_mfma_f32_16x16x32_bf16(
                        Ah[mt][ks], bl, acc[mt][nt], 0, 0, 0);
                }
            }
        }
        __syncthreads();
    }

    float* dp = dst + (size_t)ksid * ((size_t)NB * SEQ * DIM)
                    + (size_t)b * SEQ * DIM;
    #pragma unroll
    for (int mt = 0; mt < 2; ++mt) {
        #pragma unroll
        for (int r = 0; r < 4; ++r) {
            float* o = dp + (size_t)(q0 + w * 32 + mt * 16 + quad * 4 + r) * DIM + ln;
            #pragma unroll
            for (int nt = 0; nt < 8; ++nt)
                o[nt * 16] = acc[mt][nt][r];
        }
    }
}

__global__ __launch_bounds__(256) void reduce_kernel(
    const float* __restrict__ part, float* __restrict__ out, int ksplit)
{
    int idx = blockIdx.x * 256 + threadIdx.x;
    const float4* p = (const float4*)part;
    float4 a = p[idx];
    for (int s = 1; s < ksplit; ++s) {
        float4 q = p[(size_t)idx + (size_t)s * 262144];
        a.x += q.x; a.y += q.y; a.z += q.z; a.w += q.w;
    }
    ((float4*)out)[idx] = a;
}

extern "C" void kernel_launch(void* const* d_in, const int* in_sizes, int n_in,
                              void* d_out, int out_size, void* d_ws, size_t ws_size,
                              hipStream_t stream)
{
    const float* queries = (const float*)d_in[0];
    const float* keys    = (const float*)d_in[1];
    const float* values  = (const float*)d_in[2];
    const int*   valid   = (const int*)d_in[3];
    const float* Wql = (const float*)d_in[4];
    const float* bql = (const float*)d_in[5];
    const float* Wkl = (const float*)d_in[6];
    const float* bkl = (const float*)d_in[7];
    const float* Wqh = (const float*)d_in[8];
    const float* bqh = (const float*)d_in[9];
    const float* Wkh = (const float*)d_in[10];
    const float* bkh = (const float*)d_in[11];

    char* ws = (char*)d_ws;
    float* Smat = (float*)(ws);                               // 64 MB
    unsigned short* qA1 = (unsigned short*)(ws + 67108864);   // 512 KB
    unsigned short* qA2 = (unsigned short*)(ws + 67633152);   // 512 KB
    unsigned short* qA3 = (unsigned short*)(ws + 68157440);   // 512 KB
    unsigned short* kB1 = (unsigned short*)(ws + 68681728);   // 512 KB
    unsigned short* kB2 = (unsigned short*)(ws + 69206016);   // 512 KB
    float* sh    = (float*)(ws + 69730304);                   // 32 KB
    float* cmax  = (float*)(ws + 69795840);                   // 32 KB
    float* cinv  = (float*)(ws + 69828608);                   // 32 KB
    unsigned short* VthH = (unsigned short*)(ws + 69861376);  // 2 MB
    unsigned short* VthL = (unsigned short*)(ws + 71958528);  // 2 MB -> ends 74055680

    const size_t part_off = 74055680;
    const size_t pml_sz   = 8388608;                     // 8 MB
    const size_t part_sz  = (size_t)NB * SEQ * DIM * 4;  // 4 MB per split

    int fused = 0, infinal = 0, ksplit = 1;
    float2* pml = (float2*)(ws + part_off);
    float*  part = (float*)(ws + part_off);
    float*  pm = (float*)(ws + part_off);
    float*  pl = (float*)(ws + part_off + 1048576);

    if (ws_size >= part_off + pml_sz + 8 * part_sz) {
        // tier 1: non-overlapping pml + part; stats final fused into out.
        fused = 1; infinal = 1; ksplit = 8;
        pml  = (float2*)(ws + part_off);
        part = (float*)(ws + part_off + pml_sz);
    } else if (ws_size >= part_off + pml_sz) {
        // tier 2 (r16 behavior): pml overlaps part (final2 consumes pml
        // before out writes part — stream-ordered).
        fused = 1; infinal = 0;
        if      (ws_size >= part_off + 8 * part_sz) ksplit = 8;
        else if (ws_size >= part_off + 4 * part_sz) ksplit = 4;
        else if (ws_size >= part_off + 2 * part_sz) ksplit = 2;
    } else {
        // tier 3: no pml space — colred pair on pre-patched S.
        fused = 0; infinal = 0;
        if      (ws_size >= part_off + 8 * part_sz) ksplit = 8;
        else if (ws_size >= part_off + 4 * part_sz) ksplit = 4;
        else if (ws_size >= part_off + 2 * part_sz) ksplit = 2;
    }

    proj_kernel<<<dim3((NB * SEQ) / 16), 256, 0, stream>>>(
        queries, keys, Wql, bql, Wkl, bkl, Wqh, bqh, Wkh, bkh,
        qA1, qA2, qA3, kB1, kB2, sh);

    vsplit_kernel<<<dim3(SEQ / 32, DIM / 32, NB), 256, 0, stream>>>(
        values, VthH, VthL);

    score_mfma<<<dim3((NB * SEQ) / 16), 256, 0, stream>>>(
        qA1, qA2, qA3, kB1, kB2, valid, sh, Smat, pml, fused);

    if (fused) {
        if (!infinal)
            colred_final2<<<dim3((NB * SEQ) / 64), 256, 0, stream>>>(pml, cmax, cinv);
    } else {
        colred_partial<<<dim3(SEQ / 256, 32, NB), 256, 0, stream>>>(Smat, pm, pl);
        colred_final<<<dim3((NB * SEQ) / 256), 256, 0, stream>>>(pm, pl, cmax, cinv);
    }

    if (ksplit == 1) {
        out_mfma<<<dim3(SEQ / QT, 1, NB), 256, 0, stream>>>(
            Smat, VthH, VthL, cmax, cinv, pml, (float*)d_out, SEQ, 0);
    } else {
        out_mfma<<<dim3(SEQ / QT, ksplit, NB), 256, 0, stream>>>(
            Smat, VthH, VthL, cmax, cinv, pml, part, SEQ / ksplit, infinal);
        reduce_kernel<<<(NB * SEQ * DIM / 4) / 256, 256, 0, stream>>>(
            part, (float*)d_out, ksplit);
    }
}

// Round 18
// 165.810 us; speedup vs baseline: 1.0471x; 1.0471x over previous
//
#include <hip/hip_runtime.h>
#include <float.h>
#include <math.h>

#define SEQ 2048
#define NB 4
#define DIM 128
#define DL 16
#define NEGV (-1e9f)
#define TOPK 8

#define QT 128      // q-rows per out block
#define KC 64       // k chunk staged in LDS (out kernel)
#define QCH 64      // q-chunk for colred fallback

typedef unsigned long long u64;
typedef __attribute__((ext_vector_type(8))) short short8;
typedef __attribute__((ext_vector_type(4))) float f32x4;

__device__ __forceinline__ void top8_insert(float* s, float key) {
    #pragma unroll
    for (int i = 0; i < 8; ++i) {
        float a = s[i];
        s[i] = fmaxf(a, key);
        key  = fminf(a, key);
    }
}

// merge sorted-desc top8s across the 16 lanes of a quad group (xor 1,2,4,8)
__device__ __forceinline__ float top8_merge16(float* s) {
    #pragma unroll
    for (int off = 1; off < 16; off <<= 1) {
        float o[8], t[8];
        #pragma unroll
        for (int i = 0; i < 8; ++i)
            o[i] = __shfl_xor(s[i], off, 64);
        #pragma unroll
        for (int i = 0; i < 8; ++i)
            t[i] = fmaxf(s[i], o[7 - i]);
        #pragma unroll
        for (int i = 0; i < 4; ++i) {
            float a = t[i], c = t[i + 4];
            t[i] = fmaxf(a, c); t[i + 4] = fminf(a, c);
        }
        #pragma unroll
        for (int g2 = 0; g2 < 8; g2 += 4) {
            float a = t[g2], c = t[g2 + 2];
            t[g2] = fmaxf(a, c); t[g2 + 2] = fminf(a, c);
            a = t[g2 + 1]; c = t[g2 + 3];
            t[g2 + 1] = fmaxf(a, c); t[g2 + 3] = fminf(a, c);
        }
        #pragma unroll
        for (int g1 = 0; g1 < 8; g1 += 2) {
            float a = t[g1], c = t[g1 + 1];
            t[g1] = fmaxf(a, c); t[g1 + 1] = fminf(a, c);
        }
        #pragma unroll
        for (int i = 0; i < 8; ++i) s[i] = t[i];
    }
    return s[7];
}

// bf16 round-to-nearest-even of f32 (returns 16-bit pattern)
__device__ __forceinline__ unsigned bf16_rne(float x) {
    unsigned u = __float_as_uint(x);
    return (u + 0x7FFFu + ((u >> 16) & 1u)) >> 16;
}

// ---------------------------------------------------------------------------
// Kernel A: projections. Emits PACKED bf16 MFMA operands for the score GEMM
// (3-way split, see r12) + sh[k].
// ---------------------------------------------------------------------------
__global__ __launch_bounds__(256) void proj_kernel(
    const float* __restrict__ q, const float* __restrict__ k,
    const float* __restrict__ Wql, const float* __restrict__ bql,
    const float* __restrict__ Wkl, const float* __restrict__ bkl,
    const float* __restrict__ Wqh, const float* __restrict__ bqh,
    const float* __restrict__ Wkh, const float* __restrict__ bkh,
    unsigned short* __restrict__ qA1, unsigned short* __restrict__ qA2,
    unsigned short* __restrict__ qA3,
    unsigned short* __restrict__ kB1, unsigned short* __restrict__ kB2,
    float* __restrict__ sh)
{
    __shared__ float Ws[4][DIM * DL];
    __shared__ float rowq[16][DIM];
    __shared__ float rowk[16][DIM];
    int tid = threadIdx.x;
    for (int i = tid; i < DIM * DL; i += 256) {
        Ws[0][i] = Wql[i];
        Ws[1][i] = Wkl[i];
        Ws[2][i] = Wqh[i];
        Ws[3][i] = Wkh[i];
    }
    int r0 = blockIdx.x * 16;
    for (int i = tid; i < 16 * DIM; i += 256) {
        int rr = i >> 7, cc = i & 127;
        rowq[rr][cc] = q[(size_t)(r0 + rr) * DIM + cc];
        rowk[rr][cc] = k[(size_t)(r0 + rr) * DIM + cc];
    }
    __syncthreads();
    int g = tid >> 4;
    int e = tid & 15;
    float aql = 0.f, akl = 0.f, aqh = 0.f, akh = 0.f;
    #pragma unroll 8
    for (int i = 0; i < DIM; ++i) {
        float qv = rowq[g][i], kv = rowk[g][i];
        aql = fmaf(qv, Ws[0][i * DL + e], aql);
        akl = fmaf(kv, Ws[1][i * DL + e], akl);
        aqh = fmaf(qv, Ws[2][i * DL + e], aqh);
        akh = fmaf(kv, Ws[3][i * DL + e], akh);
    }
    int t = r0 + g;
    float qv = aql + bql[e];
    float kv = akl + bkl[e];

    unsigned q1 = bf16_rne(qv);
    float q1f = __uint_as_float(q1 << 16);
    float qr1 = qv - q1f;
    unsigned q2 = bf16_rne(qr1);
    float q2f = __uint_as_float(q2 << 16);
    unsigned q3 = bf16_rne(qr1 - q2f);

    unsigned k1 = bf16_rne(kv);
    float k1f = __uint_as_float(k1 << 16);
    float kr1 = kv - k1f;
    unsigned k2 = bf16_rne(kr1);
    float k2f = __uint_as_float(k2 << 16);
    unsigned k3 = bf16_rne(kr1 - k2f);

    size_t pb = (size_t)t * 32;
    qA1[pb + e] = (unsigned short)q1; qA1[pb + 16 + e] = (unsigned short)q2;
    qA2[pb + e] = (unsigned short)q2; qA2[pb + 16 + e] = (unsigned short)q1;
    qA3[pb + e] = (unsigned short)q1; qA3[pb + 16 + e] = (unsigned short)q3;
    kB1[pb + e] = (unsigned short)k1; kB1[pb + 16 + e] = (unsigned short)k2;
    kB2[pb + e] = (unsigned short)k3; kB2[pb + 16 + e] = (unsigned short)k1;

    float qp = aqh + bqh[e];
    float kp = akh + bkh[e];
    float prod = qp * kp;
    #pragma unroll
    for (int off = 8; off >= 1; off >>= 1)
        prod += __shfl_xor(prod, off, 16);
    if (e == 0) sh[t] = 0.25f * prod;
}

// ---------------------------------------------------------------------------
// Kernel A2: V transpose + bf16 hi/lo split: VthH/VthL[b][d][k].
// ---------------------------------------------------------------------------
__global__ __launch_bounds__(256) void vsplit_kernel(
    const float* __restrict__ V, unsigned short* __restrict__ VH,
    unsigned short* __restrict__ VL)
{
    __shared__ float T[32][33];
    int kb = blockIdx.x * 32, db = blockIdx.y * 32, b = blockIdx.z;
    int tid = threadIdx.x;
    {
        int r = tid >> 3, cg = tid & 7;
        float4 v = *(const float4*)(V + ((size_t)b * SEQ + kb + r) * DIM + db + cg * 4);
        T[r][cg * 4 + 0] = v.x; T[r][cg * 4 + 1] = v.y;
        T[r][cg * 4 + 2] = v.z; T[r][cg * 4 + 3] = v.w;
    }
    __syncthreads();
    int dr = tid >> 3, kg = tid & 7;
    unsigned h[4], l[4];
    #pragma unroll
    for (int j = 0; j < 4; ++j) {
        float f = T[kg * 4 + j][dr];
        unsigned hi = bf16_rne(f);
        float hf = __uint_as_float(hi << 16);
        unsigned lo = bf16_rne(f - hf);
        h[j] = hi; l[j] = lo;
    }
    size_t o = ((size_t)b * DIM + db + dr) * SEQ + kb + kg * 4;
    *(uint2*)(VH + o) = make_uint2(h[0] | (h[1] << 16), h[2] | (h[3] << 16));
    *(uint2*)(VL + o) = make_uint2(l[0] | (l[1] << 16), l[2] | (l[3] << 16));
}

// ---------------------------------------------------------------------------
// Kernel B v12: MFMA score (r12 structure) + FUSED column partials.
// Pass 1: 3-MFMA packed-split S + per-row top8 -> thr (16-lane butterfly +
// cross-wave LDS merge). Pass 2 (do_stats): each thread owns 8 columns and
// re-reads this block's own 16 S rows, applies the lazy patch, and
// accumulates 8 independent online-softmax chains -> pml chunk.
// ---------------------------------------------------------------------------
__global__ __launch_bounds__(256) void score_mfma(
    const unsigned short* __restrict__ qA1, const unsigned short* __restrict__ qA2,
    const unsigned short* __restrict__ qA3,
    const unsigned short* __restrict__ kB1, const unsigned short* __restrict__ kB2,
    const int* __restrict__ valid_lens, const float* __restrict__ sh,
    float* __restrict__ Smat, float* __restrict__ thrv,
    float2* __restrict__ pml, int do_stats)
{
    __shared__ float red[4][16][8];   // [wave][row][top8]
    __shared__ float thr_s[16];

    int tid  = threadIdx.x;
    int lane = tid & 63;
    int wv   = tid >> 6;
    int c15  = lane & 15;
    int g    = lane >> 4;                       // quad
    int row0 = __builtin_amdgcn_readfirstlane(blockIdx.x * 16);
    int b    = row0 >> 11;
    int qi0  = row0 & (SEQ - 1);

    // A fragments (whole kernel): A[row=lane&15][k=quad*8+j]
    size_t aoff = (size_t)(row0 + c15) * 32 + g * 8;
    short8 A1 = *(const short8*)(qA1 + aoff);
    short8 A2 = *(const short8*)(qA2 + aoff);
    short8 A3 = *(const short8*)(qA3 + aoff);

    const unsigned short* kb1 = kB1 + (size_t)b * SEQ * 32;
    const unsigned short* kb2 = kB2 + (size_t)b * SEQ * 32;
    const int* vlb = valid_lens + (size_t)b * SEQ;

    float s8[4][8];
    #pragma unroll
    for (int r = 0; r < 4; ++r)
        #pragma unroll
        for (int i = 0; i < 8; ++i) s8[r][i] = -FLT_MAX;

    int rowg[4];
    #pragma unroll
    for (int r = 0; r < 4; ++r) rowg[r] = qi0 + g * 4 + r;

    for (int ct = wv * 32; ct < wv * 32 + 32; ++ct) {
        int col = ct * 16 + c15;
        size_t boff = (size_t)col * 32 + g * 8;  // B[k=quad*8+j][col]
        short8 B1 = *(const short8*)(kb1 + boff);
        short8 B2 = *(const short8*)(kb2 + boff);

        f32x4 acc = (f32x4){0.f, 0.f, 0.f, 0.f};
        acc = __builtin_amdgcn_mfma_f32_16x16x32_bf16(A1, B1, acc, 0, 0, 0);
        acc = __builtin_amdgcn_mfma_f32_16x16x32_bf16(A2, B1, acc, 0, 0, 0);
        acc = __builtin_amdgcn_mfma_f32_16x16x32_bf16(A3, B2, acc, 0, 0, 0);

        int vl = vlb[col];
        vl = vl < 0 ? 0 : (vl > SEQ - 1 ? SEQ - 1 : vl);

        // C layout: col = lane&15, row = quad*4 + reg
        float* So = Smat + (size_t)(row0 + g * 4) * SEQ + col;
        #pragma unroll
        for (int r = 0; r < 4; ++r) {
            float v = 0.25f * acc[r];
            if (vl == rowg[r]) v += NEGV;
            So[(size_t)r * SEQ] = v;
            top8_insert(s8[r], v);
        }
    }

    // merge the 16 col-slices within each quad (rows g*4+r)
    #pragma unroll
    for (int r = 0; r < 4; ++r) top8_merge16(s8[r]);

    // cross-wave merge via LDS
    if (c15 == 0) {
        #pragma unroll
        for (int r = 0; r < 4; ++r)
            #pragma unroll
            for (int i = 0; i < 8; ++i)
                red[wv][g * 4 + r][i] = s8[r][i];
    }
    __syncthreads();   // also drains all S writes (vmcnt(0)) for pass 2
    if (tid < 16) {
        float fin[8];
        #pragma unroll
        for (int i = 0; i < 8; ++i) fin[i] = red[0][tid][i];
        #pragma unroll
        for (int w2 = 1; w2 < 4; ++w2)
            #pragma unroll
            for (int i = 0; i < 8; ++i)
                top8_insert(fin, red[w2][tid][i]);
        thrv[row0 + tid] = fin[7];
        thr_s[tid] = fin[7];
    }

    if (!do_stats) return;
    __syncthreads();

    // ---- pass 2: column (q-axis) softmax partials over this block's 16 rows
    int c0 = tid * 8;
    const float* shb = sh + (size_t)b * SEQ;
    float4 sh_a = *(const float4*)(shb + c0);
    float4 sh_b = *(const float4*)(shb + c0 + 4);
    const float* Srow = Smat + (size_t)row0 * SEQ;

    float mc[8], lc[8];
    #pragma unroll
    for (int i = 0; i < 8; ++i) { mc[i] = -FLT_MAX; lc[i] = 0.f; }

    #pragma unroll 4
    for (int r = 0; r < 16; ++r) {
        float t = thr_s[r];
        float4 va = *(const float4*)(Srow + (size_t)r * SEQ + c0);
        float4 vb = *(const float4*)(Srow + (size_t)r * SEQ + c0 + 4);
        float e[8];
        e[0] = (va.x >= t) ? sh_a.x : va.x;
        e[1] = (va.y >= t) ? sh_a.y : va.y;
        e[2] = (va.z >= t) ? sh_a.z : va.z;
        e[3] = (va.w >= t) ? sh_a.w : va.w;
        e[4] = (vb.x >= t) ? sh_b.x : vb.x;
        e[5] = (vb.y >= t) ? sh_b.y : vb.y;
        e[6] = (vb.z >= t) ? sh_b.z : vb.z;
        e[7] = (vb.w >= t) ? sh_b.w : vb.w;
        #pragma unroll
        for (int i = 0; i < 8; ++i) {
            float nm = fmaxf(mc[i], e[i]);
            lc[i] = lc[i] * __expf(mc[i] - nm) + __expf(e[i] - nm);
            mc[i] = nm;
        }
    }
    int chunk = qi0 >> 4;   // 0..127 within batch
    float2* o = pml + ((size_t)b * 128 + chunk) * SEQ + c0;
    #pragma unroll
    for (int i = 0; i < 8; ++i)
        o[i] = make_float2(mc[i], lc[i]);
}

// ---------------------------------------------------------------------------
// Kernel C (fused path): final column stats over 128 chunks. 128 blocks;
// 4 thread-slices of 32 compile-time-unrolled chunks each + LDS merge.
// ---------------------------------------------------------------------------
__global__ __launch_bounds__(256) void colred_final2(
    const float2* __restrict__ pml,
    float* __restrict__ cmax, float* __restrict__ cinv)
{
    __shared__ float2 red[4][64];
    int tid = threadIdx.x;
    int c0 = tid & 63, sl = tid >> 6;
    int gcol = blockIdx.x * 64 + c0;       // 0..8191
    int b = gcol >> 11, kcol = gcol & (SEQ - 1);
    float m = -FLT_MAX, l = 0.f;
    #pragma unroll 8
    for (int i = 0; i < 32; ++i) {
        int c = sl * 32 + i;
        float2 p = pml[((size_t)b * 128 + c) * SEQ + kcol];
        float nm = fmaxf(m, p.x);
        l = l * __expf(m - nm) + p.y * __expf(p.x - nm);
        m = nm;
    }
    red[sl][c0] = make_float2(m, l);
    __syncthreads();
    if (sl == 0) {
        #pragma unroll
        for (int s = 1; s < 4; ++s) {
            float2 p = red[s][c0];
            float nm = fmaxf(m, p.x);
            l = l * __expf(m - nm) + p.y * __expf(p.x - nm);
            m = nm;
        }
        cmax[gcol] = m;
        cinv[gcol] = 1.f / l;
    }
}

// ---------------------------------------------------------------------------
// Fallback kernels (workspace too small for 8 MB pml): r11's colred pair.
// ---------------------------------------------------------------------------
__global__ __launch_bounds__(256) void colred_partial(
    const float* __restrict__ Smat, const float* __restrict__ thrv,
    const float* __restrict__ sh,
    float* __restrict__ pm, float* __restrict__ pl)
{
    int kcol = blockIdx.x * 256 + threadIdx.x;
    int qc = blockIdx.y;
    int b  = blockIdx.z;
    const float* Sp  = Smat + (size_t)b * SEQ * SEQ + (size_t)(qc * QCH) * SEQ + kcol;
    const float* thb = thrv + (size_t)b * SEQ + qc * QCH;
    float shk = sh[(size_t)b * SEQ + kcol];
    float m = -FLT_MAX, l = 0.f;
    #pragma unroll 4
    for (int qq = 0; qq < QCH; ++qq) {
        float v = Sp[(size_t)qq * SEQ];
        float t = thb[qq];
        v = (v >= t) ? shk : v;
        float nm = fmaxf(m, v);
        l = l * __expf(m - nm) + __expf(v - nm);
        m = nm;
    }
    pm[((size_t)b * 32 + qc) * SEQ + kcol] = m;
    pl[((size_t)b * 32 + qc) * SEQ + kcol] = l;
}

__global__ __launch_bounds__(256) void colred_final(
    const float* __restrict__ pm, const float* __restrict__ pl,
    float* __restrict__ cmax, float* __restrict__ cinv)
{
    int idx = blockIdx.x * 256 + threadIdx.x;
    int b = idx >> 11, kcol = idx & (SEQ - 1);
    float m = -FLT_MAX, l = 0.f;
    #pragma unroll
    for (int c = 0; c < 32; ++c) {
        float mm = pm[((size_t)b * 32 + c) * SEQ + kcol];
        float ll = pl[((size_t)b * 32 + c) * SEQ + kcol];
        float nm = fmaxf(m, mm);
        l = l * __expf(m - nm) + ll * __expf(mm - nm);
        m = nm;
    }
    cmax[idx] = m;
    cinv[idx] = 1.f / l;
}

// ---------------------------------------------------------------------------
// Kernel D: MFMA PV with lazy patch.
// ---------------------------------------------------------------------------
__global__ __launch_bounds__(256) void out_mfma(
    const float* __restrict__ Smat, const unsigned short* __restrict__ VH,
    const unsigned short* __restrict__ VL,
    const float* __restrict__ cmax, const float* __restrict__ cinv,
    const float* __restrict__ thrv, const float* __restrict__ sh,
    float* __restrict__ dst, int krange)
{
    __shared__ unsigned int VtH[DIM * 32];   // 16 KB, [d][k-words] XOR-swizzled
    __shared__ unsigned int VtL[DIM * 32];   // 16 KB

    int tid  = threadIdx.x;
    int w    = tid >> 6;
    int lane = tid & 63;
    int ln   = lane & 15;
    int quad = lane >> 4;
    int q0   = blockIdx.x * QT;
    int ksid = blockIdx.y;
    int b    = blockIdx.z;
    int kbeg = ksid * krange;

    const float* Sb = Smat + (size_t)b * SEQ * SEQ;
    const unsigned short* VHb = VH + (size_t)b * DIM * SEQ;
    const unsigned short* VLb = VL + (size_t)b * DIM * SEQ;
    const float* cm  = cmax + (size_t)b * SEQ;
    const float* ci  = cinv + (size_t)b * SEQ;
    const float* shb = sh + (size_t)b * SEQ;

    float thrm[2];
    #pragma unroll
    for (int mt = 0; mt < 2; ++mt)
        thrm[mt] = thrv[(size_t)b * SEQ + q0 + w * 32 + mt * 16 + ln];

    f32x4 acc[2][8];
    #pragma unroll
    for (int mt = 0; mt < 2; ++mt)
        #pragma unroll
        for (int nt = 0; nt < 8; ++nt)
            acc[mt][nt] = (f32x4){0.f, 0.f, 0.f, 0.f};

    int sd0   = tid >> 3;   // staging d row (0..31, +32/iter)
    int skseg = tid & 7;    // staging k-segment (16B granule)

    for (int k0 = kbeg; k0 < kbeg + krange; k0 += KC) {
        // stage V^T hi/lo chunk [128d][64k] bf16, XOR-swizzled 16B granules
        #pragma unroll
        for (int it = 0; it < 4; ++it) {
            int d = sd0 + it * 32;
            size_t go = (size_t)d * SEQ + k0 + skseg * 8;
            uint4 hv = *(const uint4*)(VHb + go);
            uint4 lv = *(const uint4*)(VLb + go);
            int wa = d * 32 + ((skseg ^ (d & 7)) << 2);
            *(uint4*)&VtH[wa] = hv;
            *(uint4*)&VtL[wa] = lv;
        }

        // P A-fragments (registers): lane holds P[q=mtile+ln][k=quad*8+j]
        short8 Ah[2][2], Al[2][2];
        #pragma unroll
        for (int ks = 0; ks < 2; ++ks) {
            int kk = k0 + ks * 32 + quad * 8;
            float4 cma = *(const float4*)(cm + kk);
            float4 cmb = *(const float4*)(cm + kk + 4);
            float4 cia = *(const float4*)(ci + kk);
            float4 cib = *(const float4*)(ci + kk + 4);
            float4 sha = *(const float4*)(shb + kk);
            float4 shx = *(const float4*)(shb + kk + 4);
            #pragma unroll
            for (int mt = 0; mt < 2; ++mt) {
                const float* Sp = Sb + (size_t)(q0 + w * 32 + mt * 16 + ln) * SEQ + kk;
                float4 sa = *(const float4*)Sp;
                float4 sb = *(const float4*)(Sp + 4);
                float t = thrm[mt];
                float e0 = (sa.x >= t) ? sha.x : sa.x;
                float e1 = (sa.y >= t) ? sha.y : sa.y;
                float e2 = (sa.z >= t) ? sha.z : sa.z;
                float e3 = (sa.w >= t) ? sha.w : sa.w;
                float e4 = (sb.x >= t) ? shx.x : sb.x;
                float e5 = (sb.y >= t) ? shx.y : sb.y;
                float e6 = (sb.z >= t) ? shx.z : sb.z;
                float e7 = (sb.w >= t) ? shx.w : sb.w;
                float p[8];
                p[0] = __expf(e0 - cma.x) * cia.x;
                p[1] = __expf(e1 - cma.y) * cia.y;
                p[2] = __expf(e2 - cma.z) * cia.z;
                p[3] = __expf(e3 - cma.w) * cia.w;
                p[4] = __expf(e4 - cmb.x) * cib.x;
                p[5] = __expf(e5 - cmb.y) * cib.y;
                p[6] = __expf(e6 - cmb.z) * cib.z;
                p[7] = __expf(e7 - cmb.w) * cib.w;
                #pragma unroll
                for (int j = 0; j < 8; ++j) {
                    unsigned hi = bf16_rne(p[j]);
                    float hf = __uint_as_float(hi << 16);
                    unsigned lo = bf16_rne(p[j] - hf);
                    Ah[mt][ks][j] = (short)hi;
                    Al[mt][ks][j] = (short)lo;
                }
            }
        }
        __syncthreads();

        #pragma unroll
        for (int nt = 0; nt < 8; ++nt) {
            int d = nt * 16 + ln;
            #pragma unroll
            for (int ks = 0; ks < 2; ++ks) {
                int kseg = ks * 4 + quad;
                int wa = d * 32 + ((kseg ^ (d & 7)) << 2);
                short8 bh = *(short8*)&VtH[wa];
                short8 bl = *(short8*)&VtL[wa];
                #pragma unroll
                for (int mt = 0; mt < 2; ++mt) {
                    acc[mt][nt] = __builtin_amdgcn_mfma_f32_16x16x32_bf16(
                        Ah[mt][ks], bh, acc[mt][nt], 0, 0, 0);
                    acc[mt][nt] = __builtin_amdgcn_mfma_f32_16x16x32_bf16(
                        Al[mt][ks], bh, acc[mt][nt], 0, 0, 0);
                    acc[mt][nt] = __builtin_amdgcn_mfma_f32_16x16x32_bf16(
                        Ah[mt][ks], bl, acc[mt][nt], 0, 0, 0);
                }
            }
        }
        __syncthreads();
    }

    float* dp = dst + (size_t)ksid * ((size_t)NB * SEQ * DIM)
                    + (size_t)b * SEQ * DIM;
    #pragma unroll
    for (int mt = 0; mt < 2; ++mt) {
        #pragma unroll
        for (int r = 0; r < 4; ++r) {
            float* o = dp + (size_t)(q0 + w * 32 + mt * 16 + quad * 4 + r) * DIM + ln;
            #pragma unroll
            for (int nt = 0; nt < 8; ++nt)
                o[nt * 16] = acc[mt][nt][r];
        }
    }
}

__global__ __launch_bounds__(256) void reduce_kernel(
    const float* __restrict__ part, float* __restrict__ out, int ksplit)
{
    int idx = blockIdx.x * 256 + threadIdx.x;
    const float4* p = (const float4*)part;
    float4 a = p[idx];
    for (int s = 1; s < ksplit; ++s) {
        float4 q = p[(size_t)idx + (size_t)s * 262144];
        a.x += q.x; a.y += q.y; a.z += q.z; a.w += q.w;
    }
    ((float4*)out)[idx] = a;
}

extern "C" void kernel_launch(void* const* d_in, const int* in_sizes, int n_in,
                              void* d_out, int out_size, void* d_ws, size_t ws_size,
                              hipStream_t stream)
{
    const float* queries = (const float*)d_in[0];
    const float* keys    = (const float*)d_in[1];
    const float* values  = (const float*)d_in[2];
    const int*   valid   = (const int*)d_in[3];
    const float* Wql = (const float*)d_in[4];
    const float* bql = (const float*)d_in[5];
    const float* Wkl = (const float*)d_in[6];
    const float* bkl = (const float*)d_in[7];
    const float* Wqh = (const float*)d_in[8];
    const float* bqh = (const float*)d_in[9];
    const float* Wkh = (const float*)d_in[10];
    const float* bkh = (const float*)d_in[11];

    char* ws = (char*)d_ws;
    float* Smat = (float*)(ws);                               // 64 MB
    unsigned short* qA1 = (unsigned short*)(ws + 67108864);   // 512 KB
    unsigned short* qA2 = (unsigned short*)(ws + 67633152);   // 512 KB
    unsigned short* qA3 = (unsigned short*)(ws + 68157440);   // 512 KB
    unsigned short* kB1 = (unsigned short*)(ws + 68681728);   // 512 KB
    unsigned short* kB2 = (unsigned short*)(ws + 69206016);   // 512 KB
    float* sh    = (float*)(ws + 69730304);                   // 32 KB
    float* thrv  = (float*)(ws + 69763072);                   // 32 KB
    float* cmax  = (float*)(ws + 69795840);                   // 32 KB
    float* cinv  = (float*)(ws + 69828608);                   // 32 KB
    unsigned short* VthH = (unsigned short*)(ws + 69861376);  // 2 MB
    unsigned short* VthL = (unsigned short*)(ws + 71958528);  // 2 MB -> ends 74055680
    // pml (8 MB, fused path) lives only until colred_final2; it overlaps the
    // part region, which is written only afterwards (stream-ordered).
    const size_t part_off = 74055680;
    float2* pml  = (float2*)(ws + part_off);            // 8 MB (fused)
    float* pm    = (float*)(ws + part_off);             // 1 MB (fallback)
    float* pl    = (float*)(ws + part_off + 1048576);   // 1 MB (fallback)
    float* part  = (float*)(ws + part_off);             // ksplit*4 MB

    const size_t part_sz  = (size_t)NB * SEQ * DIM * 4;  // 4 MB
    int ksplit = 1;
    if      (ws_size >= part_off + 8 * part_sz) ksplit = 8;
    else if (ws_size >= part_off + 4 * part_sz) ksplit = 4;
    else if (ws_size >= part_off + 2 * part_sz) ksplit = 2;

    int fused = (ws_size >= part_off + 8388608) ? 1 : 0;

    proj_kernel<<<dim3((NB * SEQ) / 16), 256, 0, stream>>>(
        queries, keys, Wql, bql, Wkl, bkl, Wqh, bqh, Wkh, bkh,
        qA1, qA2, qA3, kB1, kB2, sh);

    vsplit_kernel<<<dim3(SEQ / 32, DIM / 32, NB), 256, 0, stream>>>(
        values, VthH, VthL);

    score_mfma<<<dim3((NB * SEQ) / 16), 256, 0, stream>>>(
        qA1, qA2, qA3, kB1, kB2, valid, sh, Smat, thrv, pml, fused);

    if (fused) {
        colred_final2<<<dim3((NB * SEQ) / 64), 256, 0, stream>>>(pml, cmax, cinv);
    } else {
        colred_partial<<<dim3(SEQ / 256, 32, NB), 256, 0, stream>>>(
            Smat, thrv, sh, pm, pl);
        colred_final<<<dim3((NB * SEQ) / 256), 256, 0, stream>>>(pm, pl, cmax, cinv);
    }

    if (ksplit == 1) {
        out_mfma<<<dim3(SEQ / QT, 1, NB), 256, 0, stream>>>(
            Smat, VthH, VthL, cmax, cinv, thrv, sh, (float*)d_out, SEQ);
    } else {
        out_mfma<<<dim3(SEQ / QT, ksplit, NB), 256, 0, stream>>>(
            Smat, VthH, VthL, cmax, cinv, thrv, sh, part, SEQ / ksplit);
        reduce_kernel<<<(NB * SEQ * DIM / 4) / 256, 256, 0, stream>>>(
            part, (float*)d_out, ksplit);
    }
}

// Round 19
// 160.703 us; speedup vs baseline: 1.0804x; 1.0318x over previous
//
#include <hip/hip_runtime.h>
#include <float.h>
#include <math.h>

#define SEQ 2048
#define NB 4
#define DIM 128
#define DL 16
#define NEGV (-1e9f)
#define TOPK 8

#define QT 128      // q-rows per out block
#define KC 64       // k chunk staged in LDS (out kernel)
#define QCH 64      // q-chunk for colred fallback

#define PROJ_BLOCKS ((NB * SEQ) / 16)                  // 512
#define VSPLIT_BLOCKS ((SEQ / 32) * (DIM / 32) * NB)   // 1024

typedef unsigned long long u64;
typedef __attribute__((ext_vector_type(8))) short short8;
typedef __attribute__((ext_vector_type(4))) float f32x4;

__device__ __forceinline__ void top8_insert(float* s, float key) {
    #pragma unroll
    for (int i = 0; i < 8; ++i) {
        float a = s[i];
        s[i] = fmaxf(a, key);
        key  = fminf(a, key);
    }
}

// merge sorted-desc top8s across the 16 lanes of a quad group (xor 1,2,4,8)
__device__ __forceinline__ float top8_merge16(float* s) {
    #pragma unroll
    for (int off = 1; off < 16; off <<= 1) {
        float o[8], t[8];
        #pragma unroll
        for (int i = 0; i < 8; ++i)
            o[i] = __shfl_xor(s[i], off, 64);
        #pragma unroll
        for (int i = 0; i < 8; ++i)
            t[i] = fmaxf(s[i], o[7 - i]);
        #pragma unroll
        for (int i = 0; i < 4; ++i) {
            float a = t[i], c = t[i + 4];
            t[i] = fmaxf(a, c); t[i + 4] = fminf(a, c);
        }
        #pragma unroll
        for (int g2 = 0; g2 < 8; g2 += 4) {
            float a = t[g2], c = t[g2 + 2];
            t[g2] = fmaxf(a, c); t[g2 + 2] = fminf(a, c);
            a = t[g2 + 1]; c = t[g2 + 3];
            t[g2 + 1] = fmaxf(a, c); t[g2 + 3] = fminf(a, c);
        }
        #pragma unroll
        for (int g1 = 0; g1 < 8; g1 += 2) {
            float a = t[g1], c = t[g1 + 1];
            t[g1] = fmaxf(a, c); t[g1 + 1] = fminf(a, c);
        }
        #pragma unroll
        for (int i = 0; i < 8; ++i) s[i] = t[i];
    }
    return s[7];
}

// bf16 round-to-nearest-even of f32 (returns 16-bit pattern)
__device__ __forceinline__ unsigned bf16_rne(float x) {
    unsigned u = __float_as_uint(x);
    return (u + 0x7FFFu + ((u >> 16) & 1u)) >> 16;
}

// ---------------------------------------------------------------------------
// Kernel A (merged): blocks [0,512) do the projection work (packed bf16 MFMA
// operands, 3-way split + sh[k]); blocks [512,1536) do the V transpose +
// bf16 hi/lo split. One dispatch instead of two (launch gap ~10us); the
// kernels are data-independent so the merge is race-free. 48 KB LDS arena
// (proj's requirement; vsplit blocks run at reduced occupancy, bounded cost
// since vsplit is ~3us of streaming work).
// NOTE: r6's regression was its out_mfma prefetch change, not this merge
// (r7 isolated the out change at +29us) — the merge was never isolated.
// ---------------------------------------------------------------------------
__global__ __launch_bounds__(256) void prep_kernel(
    const float* __restrict__ q, const float* __restrict__ k,
    const float* __restrict__ V,
    const float* __restrict__ Wql, const float* __restrict__ bql,
    const float* __restrict__ Wkl, const float* __restrict__ bkl,
    const float* __restrict__ Wqh, const float* __restrict__ bqh,
    const float* __restrict__ Wkh, const float* __restrict__ bkh,
    unsigned short* __restrict__ qA1, unsigned short* __restrict__ qA2,
    unsigned short* __restrict__ qA3,
    unsigned short* __restrict__ kB1, unsigned short* __restrict__ kB2,
    float* __restrict__ sh,
    unsigned short* __restrict__ VH, unsigned short* __restrict__ VL)
{
    __shared__ float smem[12288];   // 48 KB arena
    int tid = threadIdx.x;
    int bid = blockIdx.x;

    if (bid < PROJ_BLOCKS) {
        // ---- proj ----
        float* Ws   = smem;               // [4][2048] = 8192 floats
        float* rowq = smem + 8192;        // [16][128] = 2048 floats
        float* rowk = smem + 10240;       // [16][128] = 2048 floats
        for (int i = tid; i < DIM * DL; i += 256) {
            Ws[0 * 2048 + i] = Wql[i];
            Ws[1 * 2048 + i] = Wkl[i];
            Ws[2 * 2048 + i] = Wqh[i];
            Ws[3 * 2048 + i] = Wkh[i];
        }
        int r0 = bid * 16;
        for (int i = tid; i < 16 * DIM; i += 256) {
            int rr = i >> 7, cc = i & 127;
            rowq[rr * DIM + cc] = q[(size_t)(r0 + rr) * DIM + cc];
            rowk[rr * DIM + cc] = k[(size_t)(r0 + rr) * DIM + cc];
        }
        __syncthreads();
        int g = tid >> 4;
        int e = tid & 15;
        float aql = 0.f, akl = 0.f, aqh = 0.f, akh = 0.f;
        #pragma unroll 8
        for (int i = 0; i < DIM; ++i) {
            float qv = rowq[g * DIM + i], kv = rowk[g * DIM + i];
            aql = fmaf(qv, Ws[0 * 2048 + i * DL + e], aql);
            akl = fmaf(kv, Ws[1 * 2048 + i * DL + e], akl);
            aqh = fmaf(qv, Ws[2 * 2048 + i * DL + e], aqh);
            akh = fmaf(kv, Ws[3 * 2048 + i * DL + e], akh);
        }
        int t = r0 + g;
        float qv = aql + bql[e];
        float kv = akl + bkl[e];

        unsigned q1 = bf16_rne(qv);
        float q1f = __uint_as_float(q1 << 16);
        float qr1 = qv - q1f;
        unsigned q2 = bf16_rne(qr1);
        float q2f = __uint_as_float(q2 << 16);
        unsigned q3 = bf16_rne(qr1 - q2f);

        unsigned k1 = bf16_rne(kv);
        float k1f = __uint_as_float(k1 << 16);
        float kr1 = kv - k1f;
        unsigned k2 = bf16_rne(kr1);
        float k2f = __uint_as_float(k2 << 16);
        unsigned k3 = bf16_rne(kr1 - k2f);

        size_t pb = (size_t)t * 32;
        qA1[pb + e] = (unsigned short)q1; qA1[pb + 16 + e] = (unsigned short)q2;
        qA2[pb + e] = (unsigned short)q2; qA2[pb + 16 + e] = (unsigned short)q1;
        qA3[pb + e] = (unsigned short)q1; qA3[pb + 16 + e] = (unsigned short)q3;
        kB1[pb + e] = (unsigned short)k1; kB1[pb + 16 + e] = (unsigned short)k2;
        kB2[pb + e] = (unsigned short)k3; kB2[pb + 16 + e] = (unsigned short)k1;

        float qp = aqh + bqh[e];
        float kp = akh + bkh[e];
        float prod = qp * kp;
        #pragma unroll
        for (int off = 8; off >= 1; off >>= 1)
            prod += __shfl_xor(prod, off, 16);
        if (e == 0) sh[t] = 0.25f * prod;
    } else {
        // ---- vsplit ----
        int n  = bid - PROJ_BLOCKS;
        int kb = (n & 63) * 32;
        int db = ((n >> 6) & 3) * 32;
        int b  = n >> 8;
        float (*T)[33] = (float(*)[33])smem;
        {
            int r = tid >> 3, cg = tid & 7;
            float4 v = *(const float4*)(V + ((size_t)b * SEQ + kb + r) * DIM + db + cg * 4);
            T[r][cg * 4 + 0] = v.x; T[r][cg * 4 + 1] = v.y;
            T[r][cg * 4 + 2] = v.z; T[r][cg * 4 + 3] = v.w;
        }
        __syncthreads();
        int dr = tid >> 3, kg = tid & 7;
        unsigned h[4], l[4];
        #pragma unroll
        for (int j = 0; j < 4; ++j) {
            float f = T[kg * 4 + j][dr];
            unsigned hi = bf16_rne(f);
            float hf = __uint_as_float(hi << 16);
            unsigned lo = bf16_rne(f - hf);
            h[j] = hi; l[j] = lo;
        }
        size_t o = ((size_t)b * DIM + db + dr) * SEQ + kb + kg * 4;
        *(uint2*)(VH + o) = make_uint2(h[0] | (h[1] << 16), h[2] | (h[3] << 16));
        *(uint2*)(VL + o) = make_uint2(l[0] | (l[1] << 16), l[2] | (l[3] << 16));
    }
}

// ---------------------------------------------------------------------------
// Kernel B v12 (r13, unchanged): MFMA score + FUSED column partials.
// ---------------------------------------------------------------------------
__global__ __launch_bounds__(256) void score_mfma(
    const unsigned short* __restrict__ qA1, const unsigned short* __restrict__ qA2,
    const unsigned short* __restrict__ qA3,
    const unsigned short* __restrict__ kB1, const unsigned short* __restrict__ kB2,
    const int* __restrict__ valid_lens, const float* __restrict__ sh,
    float* __restrict__ Smat, float* __restrict__ thrv,
    float2* __restrict__ pml, int do_stats)
{
    __shared__ float red[4][16][8];   // [wave][row][top8]
    __shared__ float thr_s[16];

    int tid  = threadIdx.x;
    int lane = tid & 63;
    int wv   = tid >> 6;
    int c15  = lane & 15;
    int g    = lane >> 4;                       // quad
    int row0 = __builtin_amdgcn_readfirstlane(blockIdx.x * 16);
    int b    = row0 >> 11;
    int qi0  = row0 & (SEQ - 1);

    // A fragments (whole kernel): A[row=lane&15][k=quad*8+j]
    size_t aoff = (size_t)(row0 + c15) * 32 + g * 8;
    short8 A1 = *(const short8*)(qA1 + aoff);
    short8 A2 = *(const short8*)(qA2 + aoff);
    short8 A3 = *(const short8*)(qA3 + aoff);

    const unsigned short* kb1 = kB1 + (size_t)b * SEQ * 32;
    const unsigned short* kb2 = kB2 + (size_t)b * SEQ * 32;
    const int* vlb = valid_lens + (size_t)b * SEQ;

    float s8[4][8];
    #pragma unroll
    for (int r = 0; r < 4; ++r)
        #pragma unroll
        for (int i = 0; i < 8; ++i) s8[r][i] = -FLT_MAX;

    int rowg[4];
    #pragma unroll
    for (int r = 0; r < 4; ++r) rowg[r] = qi0 + g * 4 + r;

    for (int ct = wv * 32; ct < wv * 32 + 32; ++ct) {
        int col = ct * 16 + c15;
        size_t boff = (size_t)col * 32 + g * 8;  // B[k=quad*8+j][col]
        short8 B1 = *(const short8*)(kb1 + boff);
        short8 B2 = *(const short8*)(kb2 + boff);

        f32x4 acc = (f32x4){0.f, 0.f, 0.f, 0.f};
        acc = __builtin_amdgcn_mfma_f32_16x16x32_bf16(A1, B1, acc, 0, 0, 0);
        acc = __builtin_amdgcn_mfma_f32_16x16x32_bf16(A2, B1, acc, 0, 0, 0);
        acc = __builtin_amdgcn_mfma_f32_16x16x32_bf16(A3, B2, acc, 0, 0, 0);

        int vl = vlb[col];
        vl = vl < 0 ? 0 : (vl > SEQ - 1 ? SEQ - 1 : vl);

        // C layout: col = lane&15, row = quad*4 + reg
        float* So = Smat + (size_t)(row0 + g * 4) * SEQ + col;
        #pragma unroll
        for (int r = 0; r < 4; ++r) {
            float v = 0.25f * acc[r];
            if (vl == rowg[r]) v += NEGV;
            So[(size_t)r * SEQ] = v;
            top8_insert(s8[r], v);
        }
    }

    // merge the 16 col-slices within each quad (rows g*4+r)
    #pragma unroll
    for (int r = 0; r < 4; ++r) top8_merge16(s8[r]);

    // cross-wave merge via LDS
    if (c15 == 0) {
        #pragma unroll
        for (int r = 0; r < 4; ++r)
            #pragma unroll
            for (int i = 0; i < 8; ++i)
                red[wv][g * 4 + r][i] = s8[r][i];
    }
    __syncthreads();   // also drains all S writes (vmcnt(0)) for pass 2
    if (tid < 16) {
        float fin[8];
        #pragma unroll
        for (int i = 0; i < 8; ++i) fin[i] = red[0][tid][i];
        #pragma unroll
        for (int w2 = 1; w2 < 4; ++w2)
            #pragma unroll
            for (int i = 0; i < 8; ++i)
                top8_insert(fin, red[w2][tid][i]);
        thrv[row0 + tid] = fin[7];
        thr_s[tid] = fin[7];
    }

    if (!do_stats) return;
    __syncthreads();

    // ---- pass 2: column (q-axis) softmax partials over this block's 16 rows
    int c0 = tid * 8;
    const float* shb = sh + (size_t)b * SEQ;
    float4 sh_a = *(const float4*)(shb + c0);
    float4 sh_b = *(const float4*)(shb + c0 + 4);
    const float* Srow = Smat + (size_t)row0 * SEQ;

    float mc[8], lc[8];
    #pragma unroll
    for (int i = 0; i < 8; ++i) { mc[i] = -FLT_MAX; lc[i] = 0.f; }

    #pragma unroll 4
    for (int r = 0; r < 16; ++r) {
        float t = thr_s[r];
        float4 va = *(const float4*)(Srow + (size_t)r * SEQ + c0);
        float4 vb = *(const float4*)(Srow + (size_t)r * SEQ + c0 + 4);
        float e[8];
        e[0] = (va.x >= t) ? sh_a.x : va.x;
        e[1] = (va.y >= t) ? sh_a.y : va.y;
        e[2] = (va.z >= t) ? sh_a.z : va.z;
        e[3] = (va.w >= t) ? sh_a.w : va.w;
        e[4] = (vb.x >= t) ? sh_b.x : vb.x;
        e[5] = (vb.y >= t) ? sh_b.y : vb.y;
        e[6] = (vb.z >= t) ? sh_b.z : vb.z;
        e[7] = (vb.w >= t) ? sh_b.w : vb.w;
        #pragma unroll
        for (int i = 0; i < 8; ++i) {
            float nm = fmaxf(mc[i], e[i]);
            lc[i] = lc[i] * __expf(mc[i] - nm) + __expf(e[i] - nm);
            mc[i] = nm;
        }
    }
    int chunk = qi0 >> 4;   // 0..127 within batch
    float2* o = pml + ((size_t)b * 128 + chunk) * SEQ + c0;
    #pragma unroll
    for (int i = 0; i < 8; ++i)
        o[i] = make_float2(mc[i], lc[i]);
}

// ---------------------------------------------------------------------------
// Kernel C (fused path): final column stats over 128 chunks.
// ---------------------------------------------------------------------------
__global__ __launch_bounds__(256) void colred_final2(
    const float2* __restrict__ pml,
    float* __restrict__ cmax, float* __restrict__ cinv)
{
    __shared__ float2 red[4][64];
    int tid = threadIdx.x;
    int c0 = tid & 63, sl = tid >> 6;
    int gcol = blockIdx.x * 64 + c0;       // 0..8191
    int b = gcol >> 11, kcol = gcol & (SEQ - 1);
    float m = -FLT_MAX, l = 0.f;
    #pragma unroll 8
    for (int i = 0; i < 32; ++i) {
        int c = sl * 32 + i;
        float2 p = pml[((size_t)b * 128 + c) * SEQ + kcol];
        float nm = fmaxf(m, p.x);
        l = l * __expf(m - nm) + p.y * __expf(p.x - nm);
        m = nm;
    }
    red[sl][c0] = make_float2(m, l);
    __syncthreads();
    if (sl == 0) {
        #pragma unroll
        for (int s = 1; s < 4; ++s) {
            float2 p = red[s][c0];
            float nm = fmaxf(m, p.x);
            l = l * __expf(m - nm) + p.y * __expf(p.x - nm);
            m = nm;
        }
        cmax[gcol] = m;
        cinv[gcol] = 1.f / l;
    }
}

// ---------------------------------------------------------------------------
// Fallback kernels (workspace too small for 8 MB pml).
// ---------------------------------------------------------------------------
__global__ __launch_bounds__(256) void colred_partial(
    const float* __restrict__ Smat, const float* __restrict__ thrv,
    const float* __restrict__ sh,
    float* __restrict__ pm, float* __restrict__ pl)
{
    int kcol = blockIdx.x * 256 + threadIdx.x;
    int qc = blockIdx.y;
    int b  = blockIdx.z;
    const float* Sp  = Smat + (size_t)b * SEQ * SEQ + (size_t)(qc * QCH) * SEQ + kcol;
    const float* thb = thrv + (size_t)b * SEQ + qc * QCH;
    float shk = sh[(size_t)b * SEQ + kcol];
    float m = -FLT_MAX, l = 0.f;
    #pragma unroll 4
    for (int qq = 0; qq < QCH; ++qq) {
        float v = Sp[(size_t)qq * SEQ];
        float t = thb[qq];
        v = (v >= t) ? shk : v;
        float nm = fmaxf(m, v);
        l = l * __expf(m - nm) + __expf(v - nm);
        m = nm;
    }
    pm[((size_t)b * 32 + qc) * SEQ + kcol] = m;
    pl[((size_t)b * 32 + qc) * SEQ + kcol] = l;
}

__global__ __launch_bounds__(256) void colred_final(
    const float* __restrict__ pm, const float* __restrict__ pl,
    float* __restrict__ cmax, float* __restrict__ cinv)
{
    int idx = blockIdx.x * 256 + threadIdx.x;
    int b = idx >> 11, kcol = idx & (SEQ - 1);
    float m = -FLT_MAX, l = 0.f;
    #pragma unroll
    for (int c = 0; c < 32; ++c) {
        float mm = pm[((size_t)b * 32 + c) * SEQ + kcol];
        float ll = pl[((size_t)b * 32 + c) * SEQ + kcol];
        float nm = fmaxf(m, mm);
        l = l * __expf(m - nm) + ll * __expf(mm - nm);
        m = nm;
    }
    cmax[idx] = m;
    cinv[idx] = 1.f / l;
}

// ---------------------------------------------------------------------------
// Kernel D (r13, unchanged): MFMA PV with lazy patch.
// ---------------------------------------------------------------------------
__global__ __launch_bounds__(256) void out_mfma(
    const float* __restrict__ Smat, const unsigned short* __restrict__ VH,
    const unsigned short* __restrict__ VL,
    const float* __restrict__ cmax, const float* __restrict__ cinv,
    const float* __restrict__ thrv, const float* __restrict__ sh,
    float* __restrict__ dst, int krange)
{
    __shared__ unsigned int VtH[DIM * 32];   // 16 KB, [d][k-words] XOR-swizzled
    __shared__ unsigned int VtL[DIM * 32];   // 16 KB

    int tid  = threadIdx.x;
    int w    = tid >> 6;
    int lane = tid & 63;
    int ln   = lane & 15;
    int quad = lane >> 4;
    int q0   = blockIdx.x * QT;
    int ksid = blockIdx.y;
    int b    = blockIdx.z;
    int kbeg = ksid * krange;

    const float* Sb = Smat + (size_t)b * SEQ * SEQ;
    const unsigned short* VHb = VH + (size_t)b * DIM * SEQ;
    const unsigned short* VLb = VL + (size_t)b * DIM * SEQ;
    const float* cm  = cmax + (size_t)b * SEQ;
    const float* ci  = cinv + (size_t)b * SEQ;
    const float* shb = sh + (size_t)b * SEQ;

    float thrm[2];
    #pragma unroll
    for (int mt = 0; mt < 2; ++mt)
        thrm[mt] = thrv[(size_t)b * SEQ + q0 + w * 32 + mt * 16 + ln];

    f32x4 acc[2][8];
    #pragma unroll
    for (int mt = 0; mt < 2; ++mt)
        #pragma unroll
        for (int nt = 0; nt < 8; ++nt)
            acc[mt][nt] = (f32x4){0.f, 0.f, 0.f, 0.f};

    int sd0   = tid >> 3;   // staging d row (0..31, +32/iter)
    int skseg = tid & 7;    // staging k-segment (16B granule)

    for (int k0 = kbeg; k0 < kbeg + krange; k0 += KC) {
        // stage V^T hi/lo chunk [128d][64k] bf16, XOR-swizzled 16B granules
        #pragma unroll
        for (int it = 0; it < 4; ++it) {
            int d = sd0 + it * 32;
            size_t go = (size_t)d * SEQ + k0 + skseg * 8;
            uint4 hv = *(const uint4*)(VHb + go);
            uint4 lv = *(const uint4*)(VLb + go);
            int wa = d * 32 + ((skseg ^ (d & 7)) << 2);
            *(uint4*)&VtH[wa] = hv;
            *(uint4*)&VtL[wa] = lv;
        }

        // P A-fragments (registers): lane holds P[q=mtile+ln][k=quad*8+j]
        short8 Ah[2][2], Al[2][2];
        #pragma unroll
        for (int ks = 0; ks < 2; ++ks) {
            int kk = k0 + ks * 32 + quad * 8;
            float4 cma = *(const float4*)(cm + kk);
            float4 cmb = *(const float4*)(cm + kk + 4);
            float4 cia = *(const float4*)(ci + kk);
            float4 cib = *(const float4*)(ci + kk + 4);
            float4 sha = *(const float4*)(shb + kk);
            float4 shx = *(const float4*)(shb + kk + 4);
            #pragma unroll
            for (int mt = 0; mt < 2; ++mt) {
                const float* Sp = Sb + (size_t)(q0 + w * 32 + mt * 16 + ln) * SEQ + kk;
                float4 sa = *(const float4*)Sp;
                float4 sb = *(const float4*)(Sp + 4);
                float t = thrm[mt];
                float e0 = (sa.x >= t) ? sha.x : sa.x;
                float e1 = (sa.y >= t) ? sha.y : sa.y;
                float e2 = (sa.z >= t) ? sha.z : sa.z;
                float e3 = (sa.w >= t) ? sha.w : sa.w;
                float e4 = (sb.x >= t) ? shx.x : sb.x;
                float e5 = (sb.y >= t) ? shx.y : sb.y;
                float e6 = (sb.z >= t) ? shx.z : sb.z;
                float e7 = (sb.w >= t) ? shx.w : sb.w;
                float p[8];
                p[0] = __expf(e0 - cma.x) * cia.x;
                p[1] = __expf(e1 - cma.y) * cia.y;
                p[2] = __expf(e2 - cma.z) * cia.z;
                p[3] = __expf(e3 - cma.w) * cia.w;
                p[4] = __expf(e4 - cmb.x) * cib.x;
                p[5] = __expf(e5 - cmb.y) * cib.y;
                p[6] = __expf(e6 - cmb.z) * cib.z;
                p[7] = __expf(e7 - cmb.w) * cib.w;
                #pragma unroll
                for (int j = 0; j < 8; ++j) {
                    unsigned hi = bf16_rne(p[j]);
                    float hf = __uint_as_float(hi << 16);
                    unsigned lo = bf16_rne(p[j] - hf);
                    Ah[mt][ks][j] = (short)hi;
                    Al[mt][ks][j] = (short)lo;
                }
            }
        }
        __syncthreads();

        #pragma unroll
        for (int nt = 0; nt < 8; ++nt) {
            int d = nt * 16 + ln;
            #pragma unroll
            for (int ks = 0; ks < 2; ++ks) {
                int kseg = ks * 4 + quad;
                int wa = d * 32 + ((kseg ^ (d & 7)) << 2);
                short8 bh = *(short8*)&VtH[wa];
                short8 bl = *(short8*)&VtL[wa];
                #pragma unroll
                for (int mt = 0; mt < 2; ++mt) {
                    acc[mt][nt] = __builtin_amdgcn_mfma_f32_16x16x32_bf16(
                        Ah[mt][ks], bh, acc[mt][nt], 0, 0, 0);
                    acc[mt][nt] = __builtin_amdgcn_mfma_f32_16x16x32_bf16(
                        Al[mt][ks], bh, acc[mt][nt], 0, 0, 0);
                    acc[mt][nt] = __builtin_amdgcn_mfma_f32_16x16x32_bf16(
                        Ah[mt][ks], bl, acc[mt][nt], 0, 0, 0);
                }
            }
        }
        __syncthreads();
    }

    float* dp = dst + (size_t)ksid * ((size_t)NB * SEQ * DIM)
                    + (size_t)b * SEQ * DIM;
    #pragma unroll
    for (int mt = 0; mt < 2; ++mt) {
        #pragma unroll
        for (int r = 0; r < 4; ++r) {
            float* o = dp + (size_t)(q0 + w * 32 + mt * 16 + quad * 4 + r) * DIM + ln;
            #pragma unroll
            for (int nt = 0; nt < 8; ++nt)
                o[nt * 16] = acc[mt][nt][r];
        }
    }
}

__global__ __launch_bounds__(256) void reduce_kernel(
    const float* __restrict__ part, float* __restrict__ out, int ksplit)
{
    int idx = blockIdx.x * 256 + threadIdx.x;
    const float4* p = (const float4*)part;
    float4 a = p[idx];
    for (int s = 1; s < ksplit; ++s) {
        float4 q = p[(size_t)idx + (size_t)s * 262144];
        a.x += q.x; a.y += q.y; a.z += q.z; a.w += q.w;
    }
    ((float4*)out)[idx] = a;
}

extern "C" void kernel_launch(void* const* d_in, const int* in_sizes, int n_in,
                              void* d_out, int out_size, void* d_ws, size_t ws_size,
                              hipStream_t stream)
{
    const float* queries = (const float*)d_in[0];
    const float* keys    = (const float*)d_in[1];
    const float* values  = (const float*)d_in[2];
    const int*   valid   = (const int*)d_in[3];
    const float* Wql = (const float*)d_in[4];
    const float* bql = (const float*)d_in[5];
    const float* Wkl = (const float*)d_in[6];
    const float* bkl = (const float*)d_in[7];
    const float* Wqh = (const float*)d_in[8];
    const float* bqh = (const float*)d_in[9];
    const float* Wkh = (const float*)d_in[10];
    const float* bkh = (const float*)d_in[11];

    char* ws = (char*)d_ws;
    float* Smat = (float*)(ws);                               // 64 MB
    unsigned short* qA1 = (unsigned short*)(ws + 67108864);   // 512 KB
    unsigned short* qA2 = (unsigned short*)(ws + 67633152);   // 512 KB
    unsigned short* qA3 = (unsigned short*)(ws + 68157440);   // 512 KB
    unsigned short* kB1 = (unsigned short*)(ws + 68681728);   // 512 KB
    unsigned short* kB2 = (unsigned short*)(ws + 69206016);   // 512 KB
    float* sh    = (float*)(ws + 69730304);                   // 32 KB
    float* thrv  = (float*)(ws + 69763072);                   // 32 KB
    float* cmax  = (float*)(ws + 69795840);                   // 32 KB
    float* cinv  = (float*)(ws + 69828608);                   // 32 KB
    unsigned short* VthH = (unsigned short*)(ws + 69861376);  // 2 MB
    unsigned short* VthL = (unsigned short*)(ws + 71958528);  // 2 MB -> ends 74055680
    // pml (8 MB, fused path) lives only until colred_final2; it overlaps the
    // part region, which is written only afterwards (stream-ordered).
    const size_t part_off = 74055680;
    float2* pml  = (float2*)(ws + part_off);            // 8 MB (fused)
    float* pm    = (float*)(ws + part_off);             // 1 MB (fallback)
    float* pl    = (float*)(ws + part_off + 1048576);   // 1 MB (fallback)
    float* part  = (float*)(ws + part_off);             // ksplit*4 MB

    const size_t part_sz  = (size_t)NB * SEQ * DIM * 4;  // 4 MB
    int ksplit = 1;
    if      (ws_size >= part_off + 8 * part_sz) ksplit = 8;
    else if (ws_size >= part_off + 4 * part_sz) ksplit = 4;
    else if (ws_size >= part_off + 2 * part_sz) ksplit = 2;

    int fused = (ws_size >= part_off + 8388608) ? 1 : 0;

    prep_kernel<<<dim3(PROJ_BLOCKS + VSPLIT_BLOCKS), 256, 0, stream>>>(
        queries, keys, values, Wql, bql, Wkl, bkl, Wqh, bqh, Wkh, bkh,
        qA1, qA2, qA3, kB1, kB2, sh, VthH, VthL);

    score_mfma<<<dim3((NB * SEQ) / 16), 256, 0, stream>>>(
        qA1, qA2, qA3, kB1, kB2, valid, sh, Smat, thrv, pml, fused);

    if (fused) {
        colred_final2<<<dim3((NB * SEQ) / 64), 256, 0, stream>>>(pml, cmax, cinv);
    } else {
        colred_partial<<<dim3(SEQ / 256, 32, NB), 256, 0, stream>>>(
            Smat, thrv, sh, pm, pl);
        colred_final<<<dim3((NB * SEQ) / 256), 256, 0, stream>>>(pm, pl, cmax, cinv);
    }

    if (ksplit == 1) {
        out_mfma<<<dim3(SEQ / QT, 1, NB), 256, 0, stream>>>(
            Smat, VthH, VthL, cmax, cinv, thrv, sh, (float*)d_out, SEQ);
    } else {
        out_mfma<<<dim3(SEQ / QT, ksplit, NB), 256, 0, stream>>>(
            Smat, VthH, VthL, cmax, cinv, thrv, sh, part, SEQ / ksplit);
        reduce_kernel<<<(NB * SEQ * DIM / 4) / 256, 256, 0, stream>>>(
            part, (float*)d_out, ksplit);
    }
}